// Round 13
// baseline (1134.526 us; speedup 1.0000x reference)
//
#include <hip/hip_runtime.h>

typedef unsigned int u32;

#define NTOK 131072
#define DIMS 1024
#define NT   256

using bf16x8 = __attribute__((ext_vector_type(8))) short;
using f32x4  = __attribute__((ext_vector_type(4))) float;

// d_ws layout:
//   [0, 1MB)      Bf : bf16[2][32][64][16][8]  B-fragments, plane-major
//                 flat elem = (((p*32+ks)*64 + L)*16 + n)*8 + j
//                 holds plane_p(sig[t = 16n + (L&15)][d = ks*32 + (L>>4)*8 + j])
//   [1MB, +1KB)   Sv : float[256]  per-tile nonzero count
#define BF_OFF 0
#define SV_OFF (1 << 20)

// dist = Su + Sv - dot(a,b) - dot(u,v), a=sign(x), u=|a|, b=sign(s), v=|b|
// (exact: 2*(px*ps+nx*ns) = a*b + u*v elementwise; all sums ≤2048, exact f32)
__device__ __forceinline__ short sgnbf(float v) {
    return v > 0.f ? (short)0x3F80 : (v < 0.f ? (short)0xBF80 : (short)0);
}
__device__ __forceinline__ short absbf(float v) {
    return v != 0.f ? (short)0x3F80 : (short)0;
}

// ---------------------------------------------------------------------------
// Kernel A: build B-fragments (bf16 sign/abs planes) in MFMA layout + Sv.
// Block t (256 blocks x 64 lanes): lane l covers ks=l>>1, g in {2*(l&1), +1}.
// ---------------------------------------------------------------------------
__global__ void sig_kernel(const float* __restrict__ base,
                           const float* __restrict__ deltas,
                           short* __restrict__ Bf,
                           float* __restrict__ Sv)
{
    const int t  = blockIdx.x;
    const int l  = threadIdx.x;
    const int ks = l >> 1;
    int nz = 0;
    #pragma unroll
    for (int gh = 0; gh < 2; ++gh) {
        const int g = (l & 1) * 2 + gh;
        bf16x8 a8, u8;
        #pragma unroll
        for (int j = 0; j < 8; ++j) {
            const int d  = ks * 32 + g * 8 + j;
            const float b  = base[d];
            const float dl = (t > 0) ? deltas[(size_t)(t - 1) * DIMS + d] : 0.f;
            const float s  = (dl != 0.f) ? dl : b;   // sig sign source
            a8[j] = sgnbf(s);
            u8[j] = absbf(s);
            nz += (s != 0.f) ? 1 : 0;
        }
        const int L = g * 16 + (t & 15);
        const int n = t >> 4;
        size_t e0 = ((((size_t)0 * 32 + ks) * 64 + L) * 16 + n) * 8;
        size_t e1 = ((((size_t)1 * 32 + ks) * 64 + L) * 16 + n) * 8;
        *(bf16x8*)(Bf + e0) = a8;
        *(bf16x8*)(Bf + e1) = u8;
    }
    #pragma unroll
    for (int off = 1; off < 64; off <<= 1) nz += __shfl_xor(nz, off);
    if (l == 0) Sv[t] = (float)nz;
}

// ---------------------------------------------------------------------------
// Kernel B: MFMA distance kernel. 256 thr = 4 independent waves; wave owns
// 16 tokens x all 256 tiles (16 subtiles). No LDS, no barriers, no ballots.
// Per k-step (32 dims): 2 coalesced dwordx4 A-loads + in-reg sign/abs bf16
// conversion + 32 B-frag loads (imm-offset, L1/L2-hot) + 32 MFMA into 16
// independent f32x4 accumulators. Epilogue: Su via 2 shfl_xor, Sv table,
// dist = Su+Sv-acc, per-token argmin via 4 shfl_xor min.
// A-frag: lane holds x[tok0+(L&15)][ks*32+(L>>4)*8+j]; B-frag same (g,j)->d
// mapping (A/B k-layouts symmetric -> any consistent bijection is exact).
// D (m89-verified): row=(L>>4)*4+reg, col=L&15.
// ---------------------------------------------------------------------------
__global__ __launch_bounds__(256, 2)
void dist_kernel(const float* __restrict__ x,
                 const short* __restrict__ Bf,
                 const float* __restrict__ Sv,
                 float* __restrict__ idx_out,
                 float* __restrict__ dist_out)
{
    const int lane = threadIdx.x & 63;
    const int w    = threadIdx.x >> 6;
    const int tok0 = blockIdx.x * 64 + w * 16;
    const int mrow = lane & 15;
    const int g    = lane >> 4;

    const float* __restrict__ xrow = x + (size_t)(tok0 + mrow) * DIMS + g * 8;

    f32x4 acc[16];
    #pragma unroll
    for (int n = 0; n < 16; ++n) acc[n] = (f32x4){0.f, 0.f, 0.f, 0.f};

    int nz = 0;
    for (int ks = 0; ks < 32; ++ks) {
        const float4 v0 = *(const float4*)(xrow + ks * 32);
        const float4 v1 = *(const float4*)(xrow + ks * 32 + 4);

        bf16x8 af, uf;
        af[0] = sgnbf(v0.x); af[1] = sgnbf(v0.y); af[2] = sgnbf(v0.z); af[3] = sgnbf(v0.w);
        af[4] = sgnbf(v1.x); af[5] = sgnbf(v1.y); af[6] = sgnbf(v1.z); af[7] = sgnbf(v1.w);
        uf[0] = absbf(v0.x); uf[1] = absbf(v0.y); uf[2] = absbf(v0.z); uf[3] = absbf(v0.w);
        uf[4] = absbf(v1.x); uf[5] = absbf(v1.y); uf[6] = absbf(v1.z); uf[7] = absbf(v1.w);
        nz += (v0.x != 0.f) + (v0.y != 0.f) + (v0.z != 0.f) + (v0.w != 0.f)
            + (v1.x != 0.f) + (v1.y != 0.f) + (v1.z != 0.f) + (v1.w != 0.f);

        const short* __restrict__ b0 = Bf + ((size_t)ks        * 64 + lane) * 128;
        const short* __restrict__ b1 = Bf + ((size_t)(32 + ks) * 64 + lane) * 128;
        #pragma unroll
        for (int n = 0; n < 16; ++n) {
            const bf16x8 ba = *(const bf16x8*)(b0 + n * 8);
            acc[n] = __builtin_amdgcn_mfma_f32_16x16x32_bf16(af, ba, acc[n], 0, 0, 0);
        }
        #pragma unroll
        for (int n = 0; n < 16; ++n) {
            const bf16x8 bu = *(const bf16x8*)(b1 + n * 8);
            acc[n] = __builtin_amdgcn_mfma_f32_16x16x32_bf16(uf, bu, acc[n], 0, 0, 0);
        }
    }

    // Su per token: sum the 4 g-quarters of row mrow
    nz += __shfl_xor(nz, 16);
    nz += __shfl_xor(nz, 32);
    const float su = (float)nz;
    float sur[4];
    #pragma unroll
    for (int r = 0; r < 4; ++r) sur[r] = __shfl(su, g * 4 + r);   // Su of token g*4+r

    int key[4] = {0x7fffffff, 0x7fffffff, 0x7fffffff, 0x7fffffff};
    #pragma unroll
    for (int n = 0; n < 16; ++n) {
        const int   tile = n * 16 + mrow;
        const float sv   = Sv[tile];
        #pragma unroll
        for (int r = 0; r < 4; ++r) {
            const float dv = sur[r] + sv - acc[n][r];
            dist_out[(size_t)(tok0 + g * 4 + r) * NT + tile] = dv;
            key[r] = min(key[r], ((int)dv << 8) | tile);
        }
    }
    #pragma unroll
    for (int off = 1; off < 16; off <<= 1) {
        #pragma unroll
        for (int r = 0; r < 4; ++r)
            key[r] = min(key[r], __shfl_xor(key[r], off));
    }
    if (mrow == 0) {
        #pragma unroll
        for (int r = 0; r < 4; ++r)
            idx_out[tok0 + g * 4 + r] = (float)(key[r] & 255);
    }
}

extern "C" void kernel_launch(void* const* d_in, const int* in_sizes, int n_in,
                              void* d_out, int out_size, void* d_ws, size_t ws_size,
                              hipStream_t stream)
{
    const float* x      = (const float*)d_in[0];
    const float* base   = (const float*)d_in[1];
    const float* deltas = (const float*)d_in[2];

    short* Bf = (short*)((char*)d_ws + BF_OFF);      // 1 MB B-fragments
    float* Sv = (float*)((char*)d_ws + SV_OFF);      // 256 floats

    float* idx_out  = (float*)d_out;                 // N floats (tile indices)
    float* dist_out = idx_out + NTOK;                // N*T floats

    sig_kernel<<<NT, 64, 0, stream>>>(base, deltas, Bf, Sv);
    dist_kernel<<<NTOK / 64, 256, 0, stream>>>(x, Bf, Sv, idx_out, dist_out);
}

// Round 14
// 197.056 us; speedup vs baseline: 5.7574x; 5.7574x over previous
//
#include <hip/hip_runtime.h>

typedef unsigned int u32;

#define NTOK 131072
#define DIMS 1024
#define NT   256

using bf16x8 = __attribute__((ext_vector_type(8))) short;
using f32x4  = __attribute__((ext_vector_type(4))) float;

// d_ws layout:
//   [0, 1MB)        Bf : bf16[2][32][64][16][8]; slice (p,ks) = 16KB;
//                   within slice: L*128 + slot*8 shorts, slot = n ^ (L&15)
//                   (XOR slot-swizzle -> conflict-free ds_read_b128 later)
//   [1MB, +1KB)     Sv : float[256]   per-tile nonzero count (slow path)
//   [1MB+1KB, ..)   flags : int[256]  per-tile "sig has exact zero" flag
#define BF_OFF   0
#define SV_OFF   (1 << 20)
#define FLAG_OFF ((1 << 20) + 1024)

// dist = Su + Sv - dot(a,b) - dot(u,v)  [R13-verified, exact]
// and dot(u,v) = 1024 - Zu - Zv + dot(zu,zv)  =>
// if sig has NO exact zeros: dist = 1024 - dot(a,b) exactly (any x).
__device__ __forceinline__ short sgnbf(float v) {
    return v > 0.f ? (short)0x3F80 : (v < 0.f ? (short)0xBF80 : (short)0);
}
__device__ __forceinline__ short absbf(float v) {
    return v != 0.f ? (short)0x3F80 : (short)0;
}

// ---------------------------------------------------------------------------
// Kernel A: B-fragments (bf16 sign/abs planes) in MFMA layout, slot-swizzled.
// Block t, lane l: ks = l>>1, g in {2*(l&1), 2*(l&1)+1}; covers 16 dims.
// ---------------------------------------------------------------------------
__global__ void sig_kernel(const float* __restrict__ base,
                           const float* __restrict__ deltas,
                           short* __restrict__ Bf,
                           float* __restrict__ Sv,
                           int* __restrict__ flags)
{
    const int t  = blockIdx.x;
    const int l  = threadIdx.x;
    const int ks = l >> 1;
    int nz = 0, zany = 0;
    #pragma unroll
    for (int gh = 0; gh < 2; ++gh) {
        const int g = (l & 1) * 2 + gh;
        bf16x8 a8, u8;
        #pragma unroll
        for (int j = 0; j < 8; ++j) {
            const int d  = ks * 32 + g * 8 + j;
            const float b  = base[d];
            const float dl = (t > 0) ? deltas[(size_t)(t - 1) * DIMS + d] : 0.f;
            const float s  = (dl != 0.f) ? dl : b;
            a8[j] = sgnbf(s);
            u8[j] = absbf(s);
            nz   += (s != 0.f) ? 1 : 0;
            zany |= (s == 0.f) ? 1 : 0;
        }
        const int L    = g * 16 + (t & 15);
        const int n    = t >> 4;
        const int slot = n ^ (t & 15);           // == n ^ (L&15)
        const size_t off = (size_t)L * 128 + slot * 8;
        *(bf16x8*)(Bf + (((size_t)0 * 32 + ks) << 13) + off) = a8;
        *(bf16x8*)(Bf + (((size_t)1 * 32 + ks) << 13) + off) = u8;
    }
    #pragma unroll
    for (int off = 1; off < 64; off <<= 1) nz += __shfl_xor(nz, off);
    const bool za = __any(zany != 0);
    if (l == 0) { Sv[t] = (float)nz; flags[t] = za ? 1 : 0; }
}

// ---------------------------------------------------------------------------
// Kernel B: MFMA dist. 256 thr = 4 waves; block = 128 tokens (wave: 32 = 2
// m-frags) x 256 tiles. Per ks: LDS-staged B slice (double-buffered, reg-
// staged by all 4 waves), coalesced x loads prefetched 1 iter ahead,
// 16 ds_read_b128 (XOR-swizzled, conflict-floor) + 32 MFMA per wave.
// Fast path (sig has no zeros): plane-a only, dist = 1024 - acc.
// Slow path: both planes into same acc, dist = Su + Sv - acc (R13-verified).
// A/B/D fragment mappings identical to R13 (bit-exact verified).
// ---------------------------------------------------------------------------
__global__ __launch_bounds__(256, 2)
void dist_kernel(const float* __restrict__ x,
                 const short* __restrict__ Bf,
                 const float* __restrict__ Sv,
                 const int* __restrict__ flags,
                 float* __restrict__ idx_out,
                 float* __restrict__ dist_out)
{
    __shared__ short lds[2][2][8192];   // [buf][plane][16KB slice] = 64 KB

    const int lane = threadIdx.x & 63;
    const int w    = threadIdx.x >> 6;
    const int tok0 = blockIdx.x * 128 + w * 32;
    const int mrow = lane & 15;
    const int g    = lane >> 4;

    const int ff = flags[lane] | flags[64 + lane] | flags[128 + lane] | flags[192 + lane];
    const bool sigz = __any(ff != 0);

    const float* __restrict__ xr0 = x + (size_t)(tok0 + mrow) * DIMS + g * 8;
    const float* __restrict__ xr1 = x + (size_t)(tok0 + 16 + mrow) * DIMS + g * 8;

    f32x4 acc0[16], acc1[16];
    #pragma unroll
    for (int n = 0; n < 16; ++n) {
        acc0[n] = (f32x4){0.f, 0.f, 0.f, 0.f};
        acc1[n] = (f32x4){0.f, 0.f, 0.f, 0.f};
    }

    // reg-staged copy: wave w stages shorts [w*2048, +2048) of slice (p,ks)
    auto STAGE = [&](int b, int p, int kss) {
        const short* src = Bf + (((size_t)p * 32 + kss) << 13) + w * 2048 + lane * 8;
        short* dst = &lds[b][p][w * 2048 + lane * 8];
        #pragma unroll
        for (int i = 0; i < 4; ++i) {
            uint4 v = *(const uint4*)(src + i * 512);
            *(uint4*)(dst + i * 512) = v;
        }
    };

    // prologue: stage slice 0, issue x loads for ks=0
    STAGE(0, 0, 0);
    if (sigz) STAGE(0, 1, 0);
    float4 xv00 = *(const float4*)(xr0);
    float4 xv01 = *(const float4*)(xr0 + 4);
    float4 xv10 = *(const float4*)(xr1);
    float4 xv11 = *(const float4*)(xr1 + 4);

    int nz0 = 0, nz1 = 0;

    for (int ks = 0; ks < 32; ++ks) {
        __syncthreads();   // staged slice ks + x loads ks complete (vmcnt/lgkm drain)

        bf16x8 af0, af1, uf0, uf1;
        af0[0]=sgnbf(xv00.x); af0[1]=sgnbf(xv00.y); af0[2]=sgnbf(xv00.z); af0[3]=sgnbf(xv00.w);
        af0[4]=sgnbf(xv01.x); af0[5]=sgnbf(xv01.y); af0[6]=sgnbf(xv01.z); af0[7]=sgnbf(xv01.w);
        af1[0]=sgnbf(xv10.x); af1[1]=sgnbf(xv10.y); af1[2]=sgnbf(xv10.z); af1[3]=sgnbf(xv10.w);
        af1[4]=sgnbf(xv11.x); af1[5]=sgnbf(xv11.y); af1[6]=sgnbf(xv11.z); af1[7]=sgnbf(xv11.w);
        if (sigz) {
            uf0[0]=absbf(xv00.x); uf0[1]=absbf(xv00.y); uf0[2]=absbf(xv00.z); uf0[3]=absbf(xv00.w);
            uf0[4]=absbf(xv01.x); uf0[5]=absbf(xv01.y); uf0[6]=absbf(xv01.z); uf0[7]=absbf(xv01.w);
            uf1[0]=absbf(xv10.x); uf1[1]=absbf(xv10.y); uf1[2]=absbf(xv10.z); uf1[3]=absbf(xv10.w);
            uf1[4]=absbf(xv11.x); uf1[5]=absbf(xv11.y); uf1[6]=absbf(xv11.z); uf1[7]=absbf(xv11.w);
            nz0 += (xv00.x!=0.f)+(xv00.y!=0.f)+(xv00.z!=0.f)+(xv00.w!=0.f)
                 + (xv01.x!=0.f)+(xv01.y!=0.f)+(xv01.z!=0.f)+(xv01.w!=0.f);
            nz1 += (xv10.x!=0.f)+(xv10.y!=0.f)+(xv10.z!=0.f)+(xv10.w!=0.f)
                 + (xv11.x!=0.f)+(xv11.y!=0.f)+(xv11.z!=0.f)+(xv11.w!=0.f);
        }

        if (ks < 31) {   // prefetch next slice + next x (into other buffer / regs)
            STAGE((ks + 1) & 1, 0, ks + 1);
            if (sigz) STAGE((ks + 1) & 1, 1, ks + 1);
            xv00 = *(const float4*)(xr0 + (ks + 1) * 32);
            xv01 = *(const float4*)(xr0 + (ks + 1) * 32 + 4);
            xv10 = *(const float4*)(xr1 + (ks + 1) * 32);
            xv11 = *(const float4*)(xr1 + (ks + 1) * 32 + 4);
        }

        const short* sa = &lds[ks & 1][0][0];
        #pragma unroll
        for (int n = 0; n < 16; ++n) {
            const bf16x8 ba = *(const bf16x8*)(sa + lane * 128 + ((n ^ mrow) & 15) * 8);
            acc0[n] = __builtin_amdgcn_mfma_f32_16x16x32_bf16(af0, ba, acc0[n], 0, 0, 0);
            acc1[n] = __builtin_amdgcn_mfma_f32_16x16x32_bf16(af1, ba, acc1[n], 0, 0, 0);
        }
        if (sigz) {
            const short* su = &lds[ks & 1][1][0];
            #pragma unroll
            for (int n = 0; n < 16; ++n) {
                const bf16x8 bu = *(const bf16x8*)(su + lane * 128 + ((n ^ mrow) & 15) * 8);
                acc0[n] = __builtin_amdgcn_mfma_f32_16x16x32_bf16(uf0, bu, acc0[n], 0, 0, 0);
                acc1[n] = __builtin_amdgcn_mfma_f32_16x16x32_bf16(uf1, bu, acc1[n], 0, 0, 0);
            }
        }
    }

    // ---- epilogue ----
    float su0r[4], su1r[4];
    if (sigz) {
        nz0 += __shfl_xor(nz0, 16); nz0 += __shfl_xor(nz0, 32);
        nz1 += __shfl_xor(nz1, 16); nz1 += __shfl_xor(nz1, 32);
        const float s0 = (float)nz0, s1 = (float)nz1;
        #pragma unroll
        for (int r = 0; r < 4; ++r) {
            su0r[r] = __shfl(s0, g * 4 + r);
            su1r[r] = __shfl(s1, g * 4 + r);
        }
    }

    int key0[4] = {0x7fffffff,0x7fffffff,0x7fffffff,0x7fffffff};
    int key1[4] = {0x7fffffff,0x7fffffff,0x7fffffff,0x7fffffff};
    #pragma unroll
    for (int n = 0; n < 16; ++n) {
        const int tile = n * 16 + mrow;
        const float svv = sigz ? Sv[tile] : 0.f;
        #pragma unroll
        for (int r = 0; r < 4; ++r) {
            const float dv0 = sigz ? (su0r[r] + svv - acc0[n][r]) : (1024.f - acc0[n][r]);
            const float dv1 = sigz ? (su1r[r] + svv - acc1[n][r]) : (1024.f - acc1[n][r]);
            dist_out[(size_t)(tok0 + g * 4 + r) * NT + tile]      = dv0;
            dist_out[(size_t)(tok0 + 16 + g * 4 + r) * NT + tile] = dv1;
            key0[r] = min(key0[r], ((int)dv0 << 8) | tile);
            key1[r] = min(key1[r], ((int)dv1 << 8) | tile);
        }
    }
    #pragma unroll
    for (int off = 1; off < 16; off <<= 1) {
        #pragma unroll
        for (int r = 0; r < 4; ++r) {
            key0[r] = min(key0[r], __shfl_xor(key0[r], off));
            key1[r] = min(key1[r], __shfl_xor(key1[r], off));
        }
    }
    if (mrow == 0) {
        #pragma unroll
        for (int r = 0; r < 4; ++r) {
            idx_out[tok0 + g * 4 + r]      = (float)(key0[r] & 255);
            idx_out[tok0 + 16 + g * 4 + r] = (float)(key1[r] & 255);
        }
    }
}

extern "C" void kernel_launch(void* const* d_in, const int* in_sizes, int n_in,
                              void* d_out, int out_size, void* d_ws, size_t ws_size,
                              hipStream_t stream)
{
    const float* x      = (const float*)d_in[0];
    const float* base   = (const float*)d_in[1];
    const float* deltas = (const float*)d_in[2];

    short* Bf  = (short*)((char*)d_ws + BF_OFF);
    float* Sv  = (float*)((char*)d_ws + SV_OFF);
    int* flags = (int*)((char*)d_ws + FLAG_OFF);

    float* idx_out  = (float*)d_out;                 // N floats (tile indices)
    float* dist_out = idx_out + NTOK;                // N*T floats

    sig_kernel<<<NT, 64, 0, stream>>>(base, deltas, Bf, Sv, flags);
    dist_kernel<<<NTOK / 128, 256, 0, stream>>>(x, Bf, Sv, flags, idx_out, dist_out);
}